// Round 14
// baseline (358.975 us; speedup 1.0000x reference)
//
#include <hip/hip_runtime.h>
#include <math.h>

typedef __bf16 bf16x8 __attribute__((ext_vector_type(8)));
typedef float f32x4 __attribute__((ext_vector_type(4)));
typedef unsigned short u16;
typedef unsigned short u16x4 __attribute__((ext_vector_type(4)));
typedef unsigned short u16x8 __attribute__((ext_vector_type(8)));
typedef unsigned int u32;

#define AS1 __attribute__((address_space(1)))
#define AS3 __attribute__((address_space(3)))

static __device__ __forceinline__ float bf2f(u16 u) {
  union { u32 i; float f; } v; v.i = ((u32)u) << 16; return v.f;
}
static __device__ __forceinline__ u16 f2bf(float f) {
  union { float f; u32 i; } v; v.f = f;
  u32 r = v.i + 0x7FFFu + ((v.i >> 16) & 1u);
  return (u16)(r >> 16);
}

// ---- one-shot fp32 -> bf16 convert (memory-bound, coalesced) ----
__global__ __launch_bounds__(256)
void f32_to_bf16(const float* __restrict__ src, u16* __restrict__ dst, int n4) {
  const int gid = blockIdx.x * 256 + threadIdx.x;
  if (gid >= n4) return;
  const float4 v = ((const float4*)src)[gid];
  u16x4 p = {f2bf(v.x), f2bf(v.y), f2bf(v.z), f2bf(v.w)};
  ((u16x4*)dst)[gid] = p;
}

// ---- GEMM1 v4: 256x256, BK=64, 8 waves (2Mx4N), 4-phase counted pipeline ----
// K-split half-tiles: LDS [buf][khalf][256 rows][32 k]. Phase p of tile k
// stages group p (A-kh0, B-kh0, A-kh1, B-kh1) of tile k+1 into the OTHER
// buffer; vmcnt(4) at phases 0/2 retires exactly the group needed (FIFO
// oldest-first), never draining in steady state. Per-phase s_barrier bounds
// wave drift (stage target always != read buffer => WAR safe). Source-chunk
// swizzle ^(row>>2)&3, linear LDS dest, matched XOR on ds_read (rule 21).
template <bool CF32>
__global__ __launch_bounds__(512, 1)
void gemm_p8(const u16* __restrict__ A, const u16* __restrict__ B,
             void* __restrict__ Cp, int M, int N, int K) {
  __shared__ __align__(16) u16 Asb[2][2][256 * 32];   // 64 KB
  __shared__ __align__(16) u16 Bsb[2][2][256 * 32];   // 64 KB
  const int tid = threadIdx.x;
  const int lane = tid & 63;
  const int wid = tid >> 6;             // 0..7
  const int wr = wid >> 2, wc = wid & 3;  // 2 M-halves x 4 N-slices
  const int l15 = lane & 15, l4 = lane >> 4;
  const int m0 = blockIdx.y * 256, n0 = blockIdx.x * 256;

  // stage maps: idx=i*512+tid -> row=idx>>2, LDS slot=idx&3,
  // source chunk = slot ^ ((row>>2)&3)
  int grow[2], gch[2];
#pragma unroll
  for (int i = 0; i < 2; ++i) {
    const int idx = i * 512 + tid;
    grow[i] = idx >> 2;
    gch[i] = ((idx & 3) ^ ((grow[i] >> 2) & 3)) * 8;
  }

#define STAGE_A(KTB, KH, BB)                                                   \
  do {                                                                         \
    _Pragma("unroll") for (int i_ = 0; i_ < 2; ++i_)                           \
        __builtin_amdgcn_global_load_lds(                                      \
            (AS1 void*)(A + (size_t)(m0 + grow[i_]) * K + (KTB) + (KH) * 32 +  \
                        gch[i_]),                                              \
            (AS3 void*)(&Asb[BB][KH][(i_ * 512 + tid) * 8]), 16, 0, 0);        \
  } while (0)
#define STAGE_B(KTB, KH, BB)                                                   \
  do {                                                                         \
    _Pragma("unroll") for (int i_ = 0; i_ < 2; ++i_)                           \
        __builtin_amdgcn_global_load_lds(                                      \
            (AS1 void*)(B + (size_t)(n0 + grow[i_]) * K + (KTB) + (KH) * 32 +  \
                        gch[i_]),                                              \
            (AS3 void*)(&Bsb[BB][KH][(i_ * 512 + tid) * 8]), 16, 0, 0);        \
  } while (0)

  f32x4 acc[8][4];
  const f32x4 fzero = {0.f, 0.f, 0.f, 0.f};
#pragma unroll
  for (int i = 0; i < 8; ++i)
#pragma unroll
    for (int j = 0; j < 4; ++j) acc[i][j] = fzero;

  const int NT = K >> 6;  // 32

  // prologue: all 4 groups of tile 0, queue order A0,B0,A1,B1
  STAGE_A(0, 0, 0); STAGE_B(0, 0, 0); STAGE_A(0, 1, 0); STAGE_B(0, 1, 0);

  bf16x8 af[4], bfr[4];
  for (int k = 0; k < NT; ++k) {
    const int b = k & 1, nb = b ^ 1;
    const bool hn = (k + 1 < NT);
    const int ktn = (k + 1) << 6;

    // ---------- phase 0: kh0, m-frags 0-3 ----------
    asm volatile("s_waitcnt vmcnt(4)" ::: "memory");  // A0,B0 of k landed
    __builtin_amdgcn_s_barrier();
    __builtin_amdgcn_sched_barrier(0);
    if (hn) STAGE_A(ktn, 0, nb);
#pragma unroll
    for (int n = 0; n < 4; ++n) {
      const int rb = wc * 64 + n * 16 + l15;
      bfr[n] = *(const bf16x8*)&Bsb[b][0][rb * 32 + ((l4 ^ ((rb >> 2) & 3)) << 3)];
    }
#pragma unroll
    for (int j = 0; j < 4; ++j) {
      const int ra = wr * 128 + j * 16 + l15;
      af[j] = *(const bf16x8*)&Asb[b][0][ra * 32 + ((l4 ^ ((ra >> 2) & 3)) << 3)];
    }
    __builtin_amdgcn_s_setprio(1);
#pragma unroll
    for (int j = 0; j < 4; ++j)
#pragma unroll
      for (int n = 0; n < 4; ++n)
        acc[j][n] = __builtin_amdgcn_mfma_f32_16x16x32_bf16(af[j], bfr[n], acc[j][n], 0, 0, 0);
    __builtin_amdgcn_s_setprio(0);

    // ---------- phase 1: kh0, m-frags 4-7 (B regs reused) ----------
    __builtin_amdgcn_s_barrier();
    __builtin_amdgcn_sched_barrier(0);
    if (hn) STAGE_B(ktn, 0, nb);
#pragma unroll
    for (int j = 0; j < 4; ++j) {
      const int ra = wr * 128 + (4 + j) * 16 + l15;
      af[j] = *(const bf16x8*)&Asb[b][0][ra * 32 + ((l4 ^ ((ra >> 2) & 3)) << 3)];
    }
    __builtin_amdgcn_s_setprio(1);
#pragma unroll
    for (int j = 0; j < 4; ++j)
#pragma unroll
      for (int n = 0; n < 4; ++n)
        acc[4 + j][n] = __builtin_amdgcn_mfma_f32_16x16x32_bf16(af[j], bfr[n], acc[4 + j][n], 0, 0, 0);
    __builtin_amdgcn_s_setprio(0);

    // ---------- phase 2: kh1, m-frags 0-3 ----------
    if (hn)
      asm volatile("s_waitcnt vmcnt(4)" ::: "memory");  // A1,B1 of k landed
    else
      asm volatile("s_waitcnt vmcnt(0)" ::: "memory");
    __builtin_amdgcn_s_barrier();
    __builtin_amdgcn_sched_barrier(0);
    if (hn) STAGE_A(ktn, 1, nb);
#pragma unroll
    for (int n = 0; n < 4; ++n) {
      const int rb = wc * 64 + n * 16 + l15;
      bfr[n] = *(const bf16x8*)&Bsb[b][1][rb * 32 + ((l4 ^ ((rb >> 2) & 3)) << 3)];
    }
#pragma unroll
    for (int j = 0; j < 4; ++j) {
      const int ra = wr * 128 + j * 16 + l15;
      af[j] = *(const bf16x8*)&Asb[b][1][ra * 32 + ((l4 ^ ((ra >> 2) & 3)) << 3)];
    }
    __builtin_amdgcn_s_setprio(1);
#pragma unroll
    for (int j = 0; j < 4; ++j)
#pragma unroll
      for (int n = 0; n < 4; ++n)
        acc[j][n] = __builtin_amdgcn_mfma_f32_16x16x32_bf16(af[j], bfr[n], acc[j][n], 0, 0, 0);
    __builtin_amdgcn_s_setprio(0);

    // ---------- phase 3: kh1, m-frags 4-7 ----------
    __builtin_amdgcn_s_barrier();
    __builtin_amdgcn_sched_barrier(0);
    if (hn) STAGE_B(ktn, 1, nb);
#pragma unroll
    for (int j = 0; j < 4; ++j) {
      const int ra = wr * 128 + (4 + j) * 16 + l15;
      af[j] = *(const bf16x8*)&Asb[b][1][ra * 32 + ((l4 ^ ((ra >> 2) & 3)) << 3)];
    }
    __builtin_amdgcn_s_setprio(1);
#pragma unroll
    for (int j = 0; j < 4; ++j)
#pragma unroll
      for (int n = 0; n < 4; ++n)
        acc[4 + j][n] = __builtin_amdgcn_mfma_f32_16x16x32_bf16(af[j], bfr[n], acc[4 + j][n], 0, 0, 0);
    __builtin_amdgcn_s_setprio(0);
  }
#undef STAGE_A
#undef STAGE_B

  // C-write (r11-refcheck'd mapping): row=(lane>>4)*4+r, col=lane&15
#pragma unroll
  for (int mi = 0; mi < 8; ++mi)
#pragma unroll
    for (int r = 0; r < 4; ++r) {
      const int gm = m0 + wr * 128 + mi * 16 + l4 * 4 + r;
      if constexpr (CF32) {
        float* crow = (float*)Cp + (size_t)gm * N + n0 + wc * 64 + l15;
#pragma unroll
        for (int n = 0; n < 4; ++n) crow[n * 16] = acc[mi][n][r];
      } else {
        u16* crow = (u16*)Cp + (size_t)gm * N + n0 + wc * 64 + l15;
#pragma unroll
        for (int n = 0; n < 4; ++n) crow[n * 16] = f2bf(acc[mi][n][r]);
      }
    }
}

// ---- GEMM 128x128 (m97 structure) — output projection (512 blocks = 2 waves) ----
template <bool CF32>
__global__ __launch_bounds__(256, 2)
void gemm_bt(const u16* __restrict__ A, const u16* __restrict__ B,
             void* __restrict__ Cp, int M, int N, int K) {
  __shared__ __align__(16) u16 As[128 * 32];
  __shared__ __align__(16) u16 Bs[128 * 32];
  const int tid = threadIdx.x;
  const int lane = tid & 63;
  const int wid = tid >> 6;
  const int wr = wid >> 1, wc = wid & 1;
  const int l15 = lane & 15, l4 = lane >> 4;
  const int m0 = blockIdx.y * 128, n0 = blockIdx.x * 128;

  const f32x4 fzero = {0.f, 0.f, 0.f, 0.f};
  f32x4 acc[4][4];
#pragma unroll
  for (int i = 0; i < 4; ++i)
#pragma unroll
    for (int j = 0; j < 4; ++j) acc[i][j] = fzero;

  for (int kt = 0; kt < K; kt += 32) {
#pragma unroll
    for (int i = 0; i < 2; ++i) {
      const int c = wid * 64 + i * 256 + lane;
      const u16* ga = A + (size_t)(m0 + (c >> 2)) * K + kt + (c & 3) * 8;
      const u16* gb = B + (size_t)(n0 + (c >> 2)) * K + kt + (c & 3) * 8;
      __builtin_amdgcn_global_load_lds((AS1 void*)ga,
          (AS3 void*)(As + (size_t)(wid * 64 + i * 256) * 8), 16, 0, 0);
      __builtin_amdgcn_global_load_lds((AS1 void*)gb,
          (AS3 void*)(Bs + (size_t)(wid * 64 + i * 256) * 8), 16, 0, 0);
    }
    __syncthreads();
    bf16x8 af[4], bfr[4];
#pragma unroll
    for (int m = 0; m < 4; ++m)
      af[m] = *(const bf16x8*)&As[(wr * 64 + m * 16 + l15) * 32 + l4 * 8];
#pragma unroll
    for (int n = 0; n < 4; ++n)
      bfr[n] = *(const bf16x8*)&Bs[(wc * 64 + n * 16 + l15) * 32 + l4 * 8];
#pragma unroll
    for (int m = 0; m < 4; ++m)
#pragma unroll
      for (int n = 0; n < 4; ++n)
        acc[m][n] = __builtin_amdgcn_mfma_f32_16x16x32_bf16(af[m], bfr[n], acc[m][n], 0, 0, 0);
    __syncthreads();
  }

#pragma unroll
  for (int m = 0; m < 4; ++m)
#pragma unroll
    for (int r = 0; r < 4; ++r) {
      const int gm = m0 + wr * 64 + m * 16 + l4 * 4 + r;
      if constexpr (CF32) {
        float* crow = (float*)Cp + (size_t)gm * N + n0 + wc * 64 + l15;
#pragma unroll
        for (int n = 0; n < 4; ++n) crow[n * 16] = acc[m][n][r];
      } else {
        u16* crow = (u16*)Cp + (size_t)gm * N + n0 + wc * 64 + l15;
#pragma unroll
        for (int n = 0; n < 4; ++n) crow[n * 16] = f2bf(acc[m][n][r]);
      }
    }
}

// ---- RoPE in-place on q,k slots of qkv [B=2][T=2048][3][H=16][Dh=128] ----
__global__ __launch_bounds__(256)
void rope_kernel(u16* __restrict__ qkv, const int* __restrict__ seq_off) {
  const int idx = blockIdx.x * 256 + threadIdx.x;  // 4194304 threads
  const int d = idx & 63;
  const int h = (idx >> 6) & 15;
  const int t = (idx >> 10) & 2047;
  const int b = idx >> 21;
  const float pos = (float)(seq_off[0] + t);
  const float inv = expf((float)d * (-0.14391156509731588f));  // -ln(1e4)/64
  float sv, cv;
  sincosf(pos * inv, &sv, &cv);
  const size_t base = ((size_t)(b * 2048 + t)) * 6144 + h * 128 + d;
  const float q1 = bf2f(qkv[base]);
  const float q2 = bf2f(qkv[base + 64]);
  qkv[base] = f2bf(q1 * cv - q2 * sv);
  qkv[base + 64] = f2bf(q2 * cv + q1 * sv);
  const float k1 = bf2f(qkv[base + 2048]);
  const float k2 = bf2f(qkv[base + 2048 + 64]);
  qkv[base + 2048] = f2bf(k1 * cv - k2 * sv);
  qkv[base + 2048 + 64] = f2bf(k2 * cv + k1 * sv);
}

// ---- Flash attention v3 (round-10, unchanged) ----
__global__ __launch_bounds__(256, 2)
void attn_kernel(const u16* __restrict__ qkv, u16* __restrict__ ctx) {
  __shared__ __align__(16) u16 kbuf[2][32 * 128];
  __shared__ __align__(16) u16 vbuf[2][128 * 32];
  __shared__ __align__(16) u16 Plds[4][16 * 32];
  const int tid = threadIdx.x, lane = tid & 63, w = tid >> 6;
  const int l15 = lane & 15, l4 = lane >> 4;
  const int bh = blockIdx.y;
  const int b = bh >> 4, h = bh & 15;
  const u16* Qb = qkv + (size_t)b * 2048 * 6144 + h * 128;
  const u16* Kb = Qb + 2048;
  const u16* Vb = Qb + 4096;

  const int sp = tid & 15;
  const int sB = tid >> 4;
  const int sgp = sB & 1;
  const int swg = (((sp >> 2) ^ (sB & 3)) << 3) + ((sp & 3) << 1);
  const int ks0 = (w * 2 + 0) * 64 + lane;
  const int ks1 = (w * 2 + 1) * 64 + lane;
  const int kr0 = ks0 >> 4, kc0 = (ks0 & 15) ^ (kr0 & 15);
  const int kr1 = ks1 >> 4, kc1 = (ks1 & 15) ^ (kr1 & 15);

  const float scale = 0.08838834764831845f;
  const float M0 = 12.0f;
  const f32x4 fzero = {0.f, 0.f, 0.f, 0.f};

  for (int pass = 0; pass < 2; ++pass) {
    const int qt = pass ? (int)blockIdx.x : (31 - (int)blockIdx.x);
    const int q0 = qt * 64 + w * 16;
    const int nt_blk = qt * 2 + 2;

    bf16x8 qf[4];
#pragma unroll
    for (int c = 0; c < 4; ++c)
      qf[c] = *(const bf16x8*)(Qb + (size_t)(q0 + l15) * 6144 + c * 32 + l4 * 8);

    f32x4 o[8];
#pragma unroll
    for (int ch = 0; ch < 8; ++ch) o[ch] = fzero;
    float lpart[4] = {0.f, 0.f, 0.f, 0.f};

    __syncthreads();
    __builtin_amdgcn_global_load_lds((AS1 void*)(Kb + (size_t)kr0 * 6144 + kc0 * 8),
        (AS3 void*)(&kbuf[0][(w * 2 + 0) * 512]), 16, 0, 0);
    __builtin_amdgcn_global_load_lds((AS1 void*)(Kb + (size_t)kr1 * 6144 + kc1 * 8),
        (AS3 void*)(&kbuf[0][(w * 2 + 1) * 512]), 16, 0, 0);
    {
      const u16* vp = Vb + (size_t)(2 * sp) * 6144 + 8 * sB;
      const u16x8 v0 = *(const u16x8*)vp;
      const u16x8 v1 = *(const u16x8*)(vp + 6144);
#pragma unroll
      for (int e = 0; e < 8; ++e) {
        const int s = e ^ sgp;
        const int dh = 8 * sB + s;
        *(u32*)&vbuf[0][dh * 32 + swg] = (u32)v0[s] | ((u32)v1[s] << 16);
      }
    }
    __syncthreads();

    for (int t = 0; t < nt_blk; ++t) {
      const int cur = t & 1, nxtb = cur ^ 1;
      const int kv0 = t * 32;
      const bool has_next = (t + 1 < nt_blk);
      u16x8 v0, v1;
      if (has_next) {
        const u16* vp = Vb + (size_t)(kv0 + 32 + 2 * sp) * 6144 + 8 * sB;
        v0 = *(const u16x8*)vp;
        v1 = *(const u16x8*)(vp + 6144);
      }
      f32x4 s0 = fzero, s1 = fzero;
#pragma unroll
      for (int c = 0; c < 4; ++c) {
        const bf16x8 kf = *(const bf16x8*)&kbuf[cur][l15 * 128 + (((c * 4 + l4) ^ l15) << 3)];
        s0 = __builtin_amdgcn_mfma_f32_16x16x32_bf16(qf[c], kf, s0, 0, 0, 0);
      }
#pragma unroll
      for (int c = 0; c < 4; ++c) {
        const bf16x8 kf = *(const bf16x8*)&kbuf[cur][(16 + l15) * 128 + (((c * 4 + l4) ^ l15) << 3)];
        s1 = __builtin_amdgcn_mfma_f32_16x16x32_bf16(qf[c], kf, s1, 0, 0, 0);
      }
#pragma unroll
      for (int r = 0; r < 4; ++r) {
        const int qg = q0 + l4 * 4 + r;
        const float p0 = (kv0 + l15 <= qg) ? __expf(fmaf(s0[r], scale, -M0)) : 0.f;
        const float p1 = (kv0 + 16 + l15 <= qg) ? __expf(fmaf(s1[r], scale, -M0)) : 0.f;
        lpart[r] += p0 + p1;
        const int row = l4 * 4 + r;
        const int g0 = ((l15 >> 3) ^ l4) & 3;
        const int g1 = (((l15 >> 3) | 2) ^ l4) & 3;
        Plds[w][row * 32 + g0 * 8 + (l15 & 7)] = f2bf(p0);
        Plds[w][row * 32 + g1 * 8 + (l15 & 7)] = f2bf(p1);
      }
      __syncthreads();
      if (has_next) {
        __builtin_amdgcn_global_load_lds((AS1 void*)(Kb + (size_t)(kv0 + 32 + kr0) * 6144 + kc0 * 8),
            (AS3 void*)(&kbuf[nxtb][(w * 2 + 0) * 512]), 16, 0, 0);
        __builtin_amdgcn_global_load_lds((AS1 void*)(Kb + (size_t)(kv0 + 32 + kr1) * 6144 + kc1 * 8),
            (AS3 void*)(&kbuf[nxtb][(w * 2 + 1) * 512]), 16, 0, 0);
      }
      const bf16x8 pa = *(const bf16x8*)&Plds[w][l15 * 32 + ((l4 ^ (l15 >> 2)) << 3)];
#pragma unroll
      for (int ch = 0; ch < 8; ++ch) {
        const int dh = ch * 16 + l15;
        const int g = (l4 ^ ((2 * ch + (l15 >> 3)) & 3)) << 3;
        const bf16x8 vbf = *(const bf16x8*)&vbuf[cur][dh * 32 + g];
        o[ch] = __builtin_amdgcn_mfma_f32_16x16x32_bf16(pa, vbf, o[ch], 0, 0, 0);
      }
      if (has_next) {
#pragma unroll
        for (int e = 0; e < 8; ++e) {
          const int s = e ^ sgp;
          const int dh = 8 * sB + s;
          *(u32*)&vbuf[nxtb][dh * 32 + swg] = (u32)v0[s] | ((u32)v1[s] << 16);
        }
      }
    }
    float invl[4];
#pragma unroll
    for (int r = 0; r < 4; ++r) {
      float l = lpart[r];
      l += __shfl_xor(l, 1);
      l += __shfl_xor(l, 2);
      l += __shfl_xor(l, 4);
      l += __shfl_xor(l, 8);
      invl[r] = 1.0f / l;
    }
#pragma unroll
    for (int ch = 0; ch < 8; ++ch)
#pragma unroll
      for (int r = 0; r < 4; ++r) {
        const int gq = q0 + l4 * 4 + r;
        ctx[(size_t)(b * 2048 + gq) * 2048 + h * 128 + ch * 16 + l15] =
            f2bf(o[ch][r] * invl[r]);
      }
  }
}

extern "C" void kernel_launch(void* const* d_in, const int* in_sizes, int n_in,
                              void* d_out, int out_size, void* d_ws, size_t ws_size,
                              hipStream_t stream) {
  const float* x     = (const float*)d_in[0];   // (2,2048,2048) fp32
  const float* wqkv  = (const float*)d_in[1];   // (6144,2048) fp32
  const float* wproj = (const float*)d_in[2];   // (2048,2048) fp32
  const int*   soff  = (const int*)d_in[3];     // scalar int
  float* out = (float*)d_out;                   // (2,2048,2048) fp32

  u16* wsu    = (u16*)d_ws;
  u16* xb     = wsu;                    //  8388608 u16 (dead after gemm1)
  u16* wqkvb  = xb + 8388608;           // 12582912 u16
  u16* wprojb = wqkvb + 12582912;       //  4194304 u16
  u16* qkv    = wprojb + 4194304;       // 25165824 u16
  u16* ctx    = xb;                     // reuse xb region

  f32_to_bf16<<<8192, 256, 0, stream>>>(x, xb, 2097152);
  f32_to_bf16<<<12288, 256, 0, stream>>>(wqkv, wqkvb, 3145728);
  f32_to_bf16<<<4096, 256, 0, stream>>>(wproj, wprojb, 1048576);

  gemm_p8<false><<<dim3(24, 16), 512, 0, stream>>>(xb, wqkvb, qkv, 4096, 6144, 2048);
  rope_kernel<<<16384, 256, 0, stream>>>(qkv, soff);
  attn_kernel<<<dim3(16, 32), 256, 0, stream>>>(qkv, ctx);
  gemm_bt<true><<<dim3(16, 32), 256, 0, stream>>>(ctx, wprojb, out, 4096, 2048, 2048);
}

// Round 15
// 317.795 us; speedup vs baseline: 1.1296x; 1.1296x over previous
//
#include <hip/hip_runtime.h>
#include <math.h>

typedef __bf16 bf16x8 __attribute__((ext_vector_type(8)));
typedef float f32x4 __attribute__((ext_vector_type(4)));
typedef unsigned short u16;
typedef unsigned short u16x4 __attribute__((ext_vector_type(4)));
typedef unsigned short u16x8 __attribute__((ext_vector_type(8)));
typedef unsigned int u32;

#define AS1 __attribute__((address_space(1)))
#define AS3 __attribute__((address_space(3)))

static __device__ __forceinline__ float bf2f(u16 u) {
  union { u32 i; float f; } v; v.i = ((u32)u) << 16; return v.f;
}
static __device__ __forceinline__ u16 f2bf(float f) {
  union { float f; u32 i; } v; v.f = f;
  u32 r = v.i + 0x7FFFu + ((v.i >> 16) & 1u);
  return (u16)(r >> 16);
}

// ---- merged fp32 -> bf16 convert for all three inputs (dst contiguous) ----
__global__ __launch_bounds__(256)
void conv_all(const float* __restrict__ x, const float* __restrict__ wq,
              const float* __restrict__ wp, u16* __restrict__ dst) {
  const int gid = blockIdx.x * 256 + threadIdx.x;  // 0..6291455 (x4 elems)
  const float* src;
  int off;
  if (gid < 2097152) { src = x; off = gid; }
  else if (gid < 2097152 + 3145728) { src = wq; off = gid - 2097152; }
  else { src = wp; off = gid - (2097152 + 3145728); }
  const float4 v = ((const float4*)src)[off];
  u16x4 p = {f2bf(v.x), f2bf(v.y), f2bf(v.z), f2bf(v.w)};
  ((u16x4*)dst)[gid] = p;
}

// ---- GEMM 128x128 (m97 structure) + XCD-aware block swizzle ----
// launch_bounds(256,4): VGPR 56 + 64 acc = 120 <= 128 -> 4 blocks/CU,
// cross-block overlap hides the per-tile barrier drain.
template <bool CF32>
__global__ __launch_bounds__(256, 4)
void gemm_bt(const u16* __restrict__ A, const u16* __restrict__ B,
             void* __restrict__ Cp, int M, int N, int K) {
  __shared__ __align__(16) u16 As[128 * 32];
  __shared__ __align__(16) u16 Bs[128 * 32];
  const int tid = threadIdx.x;
  const int lane = tid & 63;
  const int wid = tid >> 6;
  const int wr = wid >> 1, wc = wid & 1;
  const int l15 = lane & 15, l4 = lane >> 4;
  // T1 XCD swizzle (bijective: nwg % 8 == 0 for both call sites)
  const int nwg = gridDim.x * gridDim.y;
  const int lin = blockIdx.y * gridDim.x + blockIdx.x;
  const int work = (lin & 7) * (nwg >> 3) + (lin >> 3);
  const int m0 = (work / gridDim.x) * 128;
  const int n0 = (work % gridDim.x) * 128;

  const f32x4 fzero = {0.f, 0.f, 0.f, 0.f};
  f32x4 acc[4][4];
#pragma unroll
  for (int i = 0; i < 4; ++i)
#pragma unroll
    for (int j = 0; j < 4; ++j) acc[i][j] = fzero;

  for (int kt = 0; kt < K; kt += 32) {
#pragma unroll
    for (int i = 0; i < 2; ++i) {
      const int c = wid * 64 + i * 256 + lane;
      const u16* ga = A + (size_t)(m0 + (c >> 2)) * K + kt + (c & 3) * 8;
      const u16* gb = B + (size_t)(n0 + (c >> 2)) * K + kt + (c & 3) * 8;
      __builtin_amdgcn_global_load_lds((AS1 void*)ga,
          (AS3 void*)(As + (size_t)(wid * 64 + i * 256) * 8), 16, 0, 0);
      __builtin_amdgcn_global_load_lds((AS1 void*)gb,
          (AS3 void*)(Bs + (size_t)(wid * 64 + i * 256) * 8), 16, 0, 0);
    }
    __syncthreads();
    bf16x8 af[4], bfr[4];
#pragma unroll
    for (int m = 0; m < 4; ++m)
      af[m] = *(const bf16x8*)&As[(wr * 64 + m * 16 + l15) * 32 + l4 * 8];
#pragma unroll
    for (int n = 0; n < 4; ++n)
      bfr[n] = *(const bf16x8*)&Bs[(wc * 64 + n * 16 + l15) * 32 + l4 * 8];
#pragma unroll
    for (int m = 0; m < 4; ++m)
#pragma unroll
      for (int n = 0; n < 4; ++n)
        acc[m][n] = __builtin_amdgcn_mfma_f32_16x16x32_bf16(af[m], bfr[n], acc[m][n], 0, 0, 0);
    __syncthreads();
  }

#pragma unroll
  for (int m = 0; m < 4; ++m)
#pragma unroll
    for (int r = 0; r < 4; ++r) {
      const int gm = m0 + wr * 64 + m * 16 + l4 * 4 + r;
      if constexpr (CF32) {
        float* crow = (float*)Cp + (size_t)gm * N + n0 + wc * 64 + l15;
#pragma unroll
        for (int n = 0; n < 4; ++n) crow[n * 16] = acc[m][n][r];
      } else {
        u16* crow = (u16*)Cp + (size_t)gm * N + n0 + wc * 64 + l15;
#pragma unroll
        for (int n = 0; n < 4; ++n) crow[n * 16] = f2bf(acc[m][n][r]);
      }
    }
}

// ---- RoPE in-place on q,k slots of qkv [B=2][T=2048][3][H=16][Dh=128] ----
__global__ __launch_bounds__(256)
void rope_kernel(u16* __restrict__ qkv, const int* __restrict__ seq_off) {
  const int idx = blockIdx.x * 256 + threadIdx.x;  // 4194304 threads
  const int d = idx & 63;
  const int h = (idx >> 6) & 15;
  const int t = (idx >> 10) & 2047;
  const int b = idx >> 21;
  const float pos = (float)(seq_off[0] + t);
  const float inv = expf((float)d * (-0.14391156509731588f));  // -ln(1e4)/64
  float sv, cv;
  sincosf(pos * inv, &sv, &cv);
  const size_t base = ((size_t)(b * 2048 + t)) * 6144 + h * 128 + d;
  const float q1 = bf2f(qkv[base]);
  const float q2 = bf2f(qkv[base + 64]);
  qkv[base] = f2bf(q1 * cv - q2 * sv);
  qkv[base + 64] = f2bf(q2 * cv + q1 * sv);
  const float k1 = bf2f(qkv[base + 2048]);
  const float k2 = bf2f(qkv[base + 2048 + 64]);
  qkv[base + 2048] = f2bf(k1 * cv - k2 * sv);
  qkv[base + 2048 + 64] = f2bf(k2 * cv + k1 * sv);
}

// ---- Flash attention v3.1: K-stage race fixed ----
// K(t+1) gll now issued BEFORE __syncthreads (barrier's vmcnt drain makes it
// visible to all waves before t+1's ds_reads); WAR covered by t-1's barrier.
__global__ __launch_bounds__(256, 2)
void attn_kernel(const u16* __restrict__ qkv, u16* __restrict__ ctx) {
  __shared__ __align__(16) u16 kbuf[2][32 * 128];
  __shared__ __align__(16) u16 vbuf[2][128 * 32];
  __shared__ __align__(16) u16 Plds[4][16 * 32];
  const int tid = threadIdx.x, lane = tid & 63, w = tid >> 6;
  const int l15 = lane & 15, l4 = lane >> 4;
  const int bh = blockIdx.y;
  const int b = bh >> 4, h = bh & 15;
  const u16* Qb = qkv + (size_t)b * 2048 * 6144 + h * 128;
  const u16* Kb = Qb + 2048;
  const u16* Vb = Qb + 4096;

  const int sp = tid & 15;
  const int sB = tid >> 4;
  const int sgp = sB & 1;
  const int swg = (((sp >> 2) ^ (sB & 3)) << 3) + ((sp & 3) << 1);
  const int ks0 = (w * 2 + 0) * 64 + lane;
  const int ks1 = (w * 2 + 1) * 64 + lane;
  const int kr0 = ks0 >> 4, kc0 = (ks0 & 15) ^ (kr0 & 15);
  const int kr1 = ks1 >> 4, kc1 = (ks1 & 15) ^ (kr1 & 15);

  const float scale = 0.08838834764831845f;
  const float M0 = 12.0f;
  const f32x4 fzero = {0.f, 0.f, 0.f, 0.f};

  for (int pass = 0; pass < 2; ++pass) {
    const int qt = pass ? (int)blockIdx.x : (31 - (int)blockIdx.x);
    const int q0 = qt * 64 + w * 16;
    const int nt_blk = qt * 2 + 2;

    bf16x8 qf[4];
#pragma unroll
    for (int c = 0; c < 4; ++c)
      qf[c] = *(const bf16x8*)(Qb + (size_t)(q0 + l15) * 6144 + c * 32 + l4 * 8);

    f32x4 o[8];
#pragma unroll
    for (int ch = 0; ch < 8; ++ch) o[ch] = fzero;
    float lpart[4] = {0.f, 0.f, 0.f, 0.f};

    __syncthreads();  // prior pass's reads drained before restaging buf0
    __builtin_amdgcn_global_load_lds((AS1 void*)(Kb + (size_t)kr0 * 6144 + kc0 * 8),
        (AS3 void*)(&kbuf[0][(w * 2 + 0) * 512]), 16, 0, 0);
    __builtin_amdgcn_global_load_lds((AS1 void*)(Kb + (size_t)kr1 * 6144 + kc1 * 8),
        (AS3 void*)(&kbuf[0][(w * 2 + 1) * 512]), 16, 0, 0);
    {
      const u16* vp = Vb + (size_t)(2 * sp) * 6144 + 8 * sB;
      const u16x8 v0 = *(const u16x8*)vp;
      const u16x8 v1 = *(const u16x8*)(vp + 6144);
#pragma unroll
      for (int e = 0; e < 8; ++e) {
        const int s = e ^ sgp;
        const int dh = 8 * sB + s;
        *(u32*)&vbuf[0][dh * 32 + swg] = (u32)v0[s] | ((u32)v1[s] << 16);
      }
    }
    __syncthreads();  // staged K(0)/V(0) visible (vmcnt+lgkm drained)

    for (int t = 0; t < nt_blk; ++t) {
      const int cur = t & 1, nxtb = cur ^ 1;
      const int kv0 = t * 32;
      const bool has_next = (t + 1 < nt_blk);
      u16x8 v0, v1;
      if (has_next) {  // V(t+1) register loads (covered by QK+softmax)
        const u16* vp = Vb + (size_t)(kv0 + 32 + 2 * sp) * 6144 + 8 * sB;
        v0 = *(const u16x8*)vp;
        v1 = *(const u16x8*)(vp + 6144);
      }
      f32x4 s0 = fzero, s1 = fzero;
#pragma unroll
      for (int c = 0; c < 4; ++c) {
        const bf16x8 kf = *(const bf16x8*)&kbuf[cur][l15 * 128 + (((c * 4 + l4) ^ l15) << 3)];
        s0 = __builtin_amdgcn_mfma_f32_16x16x32_bf16(qf[c], kf, s0, 0, 0, 0);
      }
#pragma unroll
      for (int c = 0; c < 4; ++c) {
        const bf16x8 kf = *(const bf16x8*)&kbuf[cur][(16 + l15) * 128 + (((c * 4 + l4) ^ l15) << 3)];
        s1 = __builtin_amdgcn_mfma_f32_16x16x32_bf16(qf[c], kf, s1, 0, 0, 0);
      }
      // K(t+1) stage issued BEFORE the barrier -> barrier drain publishes it
      if (has_next) {
        __builtin_amdgcn_global_load_lds((AS1 void*)(Kb + (size_t)(kv0 + 32 + kr0) * 6144 + kc0 * 8),
            (AS3 void*)(&kbuf[nxtb][(w * 2 + 0) * 512]), 16, 0, 0);
        __builtin_amdgcn_global_load_lds((AS1 void*)(Kb + (size_t)(kv0 + 32 + kr1) * 6144 + kc1 * 8),
            (AS3 void*)(&kbuf[nxtb][(w * 2 + 1) * 512]), 16, 0, 0);
      }
#pragma unroll
      for (int r = 0; r < 4; ++r) {
        const int qg = q0 + l4 * 4 + r;
        const float p0 = (kv0 + l15 <= qg) ? __expf(fmaf(s0[r], scale, -M0)) : 0.f;
        const float p1 = (kv0 + 16 + l15 <= qg) ? __expf(fmaf(s1[r], scale, -M0)) : 0.f;
        lpart[r] += p0 + p1;
        const int row = l4 * 4 + r;
        const int g0 = ((l15 >> 3) ^ l4) & 3;
        const int g1 = (((l15 >> 3) | 2) ^ l4) & 3;
        Plds[w][row * 32 + g0 * 8 + (l15 & 7)] = f2bf(p0);
        Plds[w][row * 32 + g1 * 8 + (l15 & 7)] = f2bf(p1);
      }
      __syncthreads();  // P visible; K(t+1) landed; V(t)/WAR settled
      const bf16x8 pa = *(const bf16x8*)&Plds[w][l15 * 32 + ((l4 ^ (l15 >> 2)) << 3)];
#pragma unroll
      for (int ch = 0; ch < 8; ++ch) {
        const int dh = ch * 16 + l15;
        const int g = (l4 ^ ((2 * ch + (l15 >> 3)) & 3)) << 3;
        const bf16x8 vbf = *(const bf16x8*)&vbuf[cur][dh * 32 + g];
        o[ch] = __builtin_amdgcn_mfma_f32_16x16x32_bf16(pa, vbf, o[ch], 0, 0, 0);
      }
      if (has_next) {
#pragma unroll
        for (int e = 0; e < 8; ++e) {
          const int s = e ^ sgp;
          const int dh = 8 * sB + s;
          *(u32*)&vbuf[nxtb][dh * 32 + swg] = (u32)v0[s] | ((u32)v1[s] << 16);
        }
      }
    }
    float invl[4];
#pragma unroll
    for (int r = 0; r < 4; ++r) {
      float l = lpart[r];
      l += __shfl_xor(l, 1);
      l += __shfl_xor(l, 2);
      l += __shfl_xor(l, 4);
      l += __shfl_xor(l, 8);
      invl[r] = 1.0f / l;
    }
#pragma unroll
    for (int ch = 0; ch < 8; ++ch)
#pragma unroll
      for (int r = 0; r < 4; ++r) {
        const int gq = q0 + l4 * 4 + r;
        ctx[(size_t)(b * 2048 + gq) * 2048 + h * 128 + ch * 16 + l15] =
            f2bf(o[ch][r] * invl[r]);
      }
  }
}

extern "C" void kernel_launch(void* const* d_in, const int* in_sizes, int n_in,
                              void* d_out, int out_size, void* d_ws, size_t ws_size,
                              hipStream_t stream) {
  const float* x     = (const float*)d_in[0];   // (2,2048,2048) fp32
  const float* wqkv  = (const float*)d_in[1];   // (6144,2048) fp32
  const float* wproj = (const float*)d_in[2];   // (2048,2048) fp32
  const int*   soff  = (const int*)d_in[3];     // scalar int
  float* out = (float*)d_out;                   // (2,2048,2048) fp32

  u16* wsu    = (u16*)d_ws;
  u16* xb     = wsu;                    //  8388608 u16 (dead after gemm1)
  u16* wqkvb  = xb + 8388608;           // 12582912 u16
  u16* wprojb = wqkvb + 12582912;       //  4194304 u16
  u16* qkv    = wprojb + 4194304;       // 25165824 u16
  u16* ctx    = xb;                     // reuse xb region

  conv_all<<<24576, 256, 0, stream>>>(x, wqkv, wproj, wsu);

  gemm_bt<false><<<dim3(48, 32), 256, 0, stream>>>(xb, wqkvb, qkv, 4096, 6144, 2048);
  rope_kernel<<<16384, 256, 0, stream>>>(qkv, soff);
  attn_kernel<<<dim3(16, 32), 256, 0, stream>>>(qkv, ctx);
  gemm_bt<true><<<dim3(16, 32), 256, 0, stream>>>(ctx, wprojb, out, 4096, 2048, 2048);
}